// Round 7
// baseline (119.073 us; speedup 1.0000x reference)
//
#include <hip/hip_runtime.h>

#define C_ 64
#define CI_ 32
#define N_ 4096
#define LOG2E 1.4426950408889634f

typedef __attribute__((ext_vector_type(8))) short bf16x8;
typedef __attribute__((ext_vector_type(4))) float f32x4;

__device__ __forceinline__ unsigned short f2bf_rne(float f) {
  unsigned u = __builtin_bit_cast(unsigned, f);
  unsigned r = (u + 0x7FFFu + ((u >> 16) & 1u)) >> 16;
  return (unsigned short)r;
}
__device__ __forceinline__ unsigned pack_bf2(float lo, float hi) {
  unsigned a = (__builtin_bit_cast(unsigned, lo) + 0x8000u) >> 16;
  unsigned b = (__builtin_bit_cast(unsigned, hi) + 0x8000u) & 0xFFFF0000u;
  return a | b;
}
__device__ __forceinline__ float bf2f(unsigned short v) {
  return __builtin_bit_cast(float, (unsigned)v << 16);
}
// async DMA global->LDS, 16B/lane; lds dst = wave-uniform base + lane*16
__device__ __forceinline__ void dma16(const void* gp, const void* lp) {
  __builtin_amdgcn_global_load_lds(
      (const __attribute__((address_space(1))) unsigned*)(unsigned long long)gp,
      (__attribute__((address_space(3))) unsigned*)(unsigned)(unsigned long long)lp,
      16, 0, 0);
}

// sigma (per 32-m chunk): slot p=8q+j -> m_local = 4q + (j&3) + 16*(j>>2).
// Chunked k-major layouts (2KB/chunk, DMA-contiguous, conflict-free ds_read):
//   phi2[b][ch][q][r=m_local][j]
//   g2  [b][ch][q][i][j]   value g[i][ch*32+sigma(8q+j)]
//   rden[b][ch][p] = 1/den[ch*32+sigma(p)]

// ---------------------------------------------------------------------------
// K1: projections. Grid 768 = (proj x b x 64 n-tiles of 64). 256 thr; wave =
// channel octet o, lane = one position. theta pre-scaled by log2(e).
// g2 path: LDS transpose -> coalesced uint4 chunk stores (no b16 scatter).
// ---------------------------------------------------------------------------
__global__ __launch_bounds__(256) void k1_proj(
    const float* __restrict__ supp, const float* __restrict__ ref,
    const float* __restrict__ tw, const float* __restrict__ tb,
    const float* __restrict__ pw, const float* __restrict__ pb,
    const float* __restrict__ gw, const float* __restrict__ gb,
    unsigned short* __restrict__ theta, unsigned short* __restrict__ phi2,
    unsigned short* __restrict__ g2)
{
  const int proj = blockIdx.x >> 8;
  const int rr = blockIdx.x & 255;
  const int b = rr >> 6;
  const int n0 = (rr & 63) << 6;
  const int o = __builtin_amdgcn_readfirstlane(threadIdx.x >> 6);
  const int lane = threadIdx.x & 63;
  const int n = n0 + lane;

  __shared__ float gL[CI_][66];

  const float *W, *bias, *src;
  if (proj == 0)      { W = tw; bias = tb; src = supp; }
  else if (proj == 1) { W = pw; bias = pb; src = ref; }
  else                { W = gw; bias = gb; src = ref; }

  const float* x = src + (size_t)b * (C_ * N_) + n;
  const float* Wo = W + o * 8 * C_;
  float acc[8];
#pragma unroll
  for (int k = 0; k < 8; k++) acc[k] = bias[o * 8 + k];
#pragma unroll 8
  for (int c = 0; c < C_; c++) {
    float v = x[(size_t)c * N_];
#pragma unroll
    for (int k = 0; k < 8; k++) acc[k] = fmaf(Wo[k * C_ + c], v, acc[k]);
  }

  if (proj == 0) {
    unsigned pk[4];
#pragma unroll
    for (int k = 0; k < 4; k++)
      pk[k] = (unsigned)f2bf_rne(acc[2 * k] * LOG2E) |
              ((unsigned)f2bf_rne(acc[2 * k + 1] * LOG2E) << 16);
    *(uint4*)(theta + (((size_t)b * N_ + n) << 5) + o * 8) = *(uint4*)pk;
  } else if (proj == 1) {
    // phi2: [b][ch=n>>5][q=o][r=n&31][j]  (o indexes channel octet = q)
    unsigned pk[4];
#pragma unroll
    for (int k = 0; k < 4; k++)
      pk[k] = (unsigned)f2bf_rne(acc[2 * k]) |
              ((unsigned)f2bf_rne(acc[2 * k + 1]) << 16);
    size_t off = (((size_t)b * 128 + (n >> 5)) << 10) + o * 256 + (n & 31) * 8;
    *(uint4*)(phi2 + off) = *(uint4*)pk;
  } else {
    // stage [i][m] in LDS, then write chunks coalesced in sigma-layout
#pragma unroll
    for (int k = 0; k < 8; k++) gL[o * 8 + k][lane] = acc[k];
    __syncthreads();
    const int t = threadIdx.x;
    const int c = t >> 7;          // chunk within the 64-m tile
    const int rr2 = t & 127;
    const int q = rr2 >> 5;
    const int i = rr2 & 31;
    const float* g0 = &gL[i][c * 32 + 4 * q];
    unsigned pk[4];
    pk[0] = pack_bf2(g0[0], g0[1]);
    pk[1] = pack_bf2(g0[2], g0[3]);
    pk[2] = pack_bf2(g0[16], g0[17]);
    pk[3] = pack_bf2(g0[18], g0[19]);
    size_t off = (((size_t)b * 128 + (n0 >> 5) + c) << 10) + rr2 * 8;
    *(uint4*)(g2 + off) = *(uint4*)pk;
  }
}

// ---------------------------------------------------------------------------
// K2: den[m] = sum_n exp2(f'); writes rden (sigma-ordered reciprocals).
// Grid 256 = (b x 64 m-tiles of 64). 16 waves = 256-n slices; 4 persistent
// phi B-frags (chunked phi2); depth-2 theta prefetch.
// ---------------------------------------------------------------------------
__global__ __launch_bounds__(1024) void k2_den(
    const unsigned short* __restrict__ theta, const unsigned short* __restrict__ phi2,
    float* __restrict__ rden)
{
  const int tid = threadIdx.x;
  const int wave = tid >> 6;
  const int lane = tid & 63;
  const int b = blockIdx.x >> 6;
  const int mbase = (blockIdx.x & 63) << 6;
  const int row16 = lane & 15;
  const int quad = lane >> 4;

  bf16x8 bf[4];
#pragma unroll
  for (int f = 0; f < 4; f++) {
    int ch = (mbase >> 5) + (f >> 1);
    int r = ((f & 1) << 4) + row16;
    bf[f] = *(const bf16x8*)(phi2 +
        (((size_t)b * 128 + ch) << 10) + (quad << 8) + r * 8);
  }

  const unsigned short* abase = theta +
      (((size_t)b * N_ + wave * 256 + row16) << 5) + (quad << 3);

  f32x4 zero = {0.f, 0.f, 0.f, 0.f};
  float dd[16];
#pragma unroll
  for (int k = 0; k < 16; k++) dd[k] = 0.f;

  bf16x8 a0 = *(const bf16x8*)abase;
  bf16x8 a1 = *(const bf16x8*)(abase + 512);
#pragma unroll 2
  for (int it = 0; it < 16; it++) {
    int itn = it + 2 <= 15 ? it + 2 : 15;
    bf16x8 an = *(const bf16x8*)(abase + ((size_t)itn << 9));
#pragma unroll
    for (int f = 0; f < 4; f++) {
      f32x4 ff = __builtin_amdgcn_mfma_f32_16x16x32_bf16(a0, bf[f], zero, 0, 0, 0);
#pragma unroll
      for (int r = 0; r < 4; r++) dd[f * 4 + r] += __builtin_amdgcn_exp2f(ff[r]);
    }
    a0 = a1; a1 = an;
  }

  __shared__ float denp[16][64];
#pragma unroll
  for (int f = 0; f < 4; f++) {
    // D-layout of bf[f] tile: col m' = f*16 + row16, rows n = 4*quad+r
    float v = (dd[f * 4] + dd[f * 4 + 1]) + (dd[f * 4 + 2] + dd[f * 4 + 3]);
    v += __shfl_xor(v, 16);
    v += __shfl_xor(v, 32);
    if (lane < 16) denp[wave][f * 16 + lane] = v;
  }
  __syncthreads();

  if (tid < 64) {
    int p = tid;
    int q = (p >> 3) & 3, j = p & 7;
    int ml = (p & 32) + 4 * q + (j & 3) + ((j >> 2) << 4);
    float den = 0.f;
#pragma unroll
    for (int w = 0; w < 16; w++) den += denp[w][ml];
    rden[(((size_t)b * 128 + (mbase >> 5) + (p >> 5)) << 5) + (p & 31)] = 1.0f / den;
  }
}

// ---------------------------------------------------------------------------
// K3: x1[i,n] partial over an m-eighth (512 m = 16 chunks of 32).
// Grid 1024 = (b x 32 n-tiles of 128 x 8 m-eighths); 256 thr = 4 waves x 32 n;
// launch_bounds(256,4) -> <=128 VGPR -> 4 blocks/CU (16 waves). Single 16KB
// LDS buffer, 4 phases of 4 chunks: DMA (global_load_lds) -> barrier ->
// 32 MFMA + 64 exp2 per wave -> barrier. Cross-block overlap hides drains.
// ---------------------------------------------------------------------------
__global__ __launch_bounds__(256, 4) void k3_attn(
    const unsigned short* __restrict__ theta, const unsigned short* __restrict__ phi2,
    const unsigned short* __restrict__ g2, const float* __restrict__ rden,
    unsigned short* __restrict__ x1p)
{
  const int tid = threadIdx.x;
  const int w = tid >> 6;
  const int lane = tid & 63;
  const int b = blockIdx.x >> 8;
  const int nt = (blockIdx.x >> 3) & 31;
  const int ms = blockIdx.x & 7;
  const int row16 = lane & 15;
  const int quad = lane >> 4;

  __shared__ __align__(16) unsigned short SB[4 * 2048];  // 16 KB: [chunk][phi|g]

  const int nbase = nt * 128 + w * 32;
  bf16x8 tB0 = *(const bf16x8*)(theta + (((size_t)b * N_ + nbase + row16) << 5) + (quad << 3));
  bf16x8 tB1 = *(const bf16x8*)(theta + (((size_t)b * N_ + nbase + 16 + row16) << 5) + (quad << 3));

  const size_t chunkb = (size_t)b * 128 + ms * 16;

  f32x4 zero = {0.f, 0.f, 0.f, 0.f};
  f32x4 xa0 = zero, xb0 = zero, xa1 = zero, xb1 = zero;

  for (int ph = 0; ph < 4; ph++) {
    // DMA 16KB: 16 x 1KB segments, 4 per wave
#pragma unroll
    for (int s = 0; s < 4; s++) {
      int idx = w * 4 + s;
      int c = idx >> 2;
      int seg = idx & 3;                 // 0:phi-lo 1:phi-hi 2:g-lo 3:g-hi
      const unsigned short* src = (seg >= 2 ? g2 : phi2) +
          ((chunkb + ph * 4 + c) << 10) + ((seg & 1) << 9) + lane * 8;
      const unsigned short* dst = SB + c * 2048 + (seg >= 2 ? 1024 : 0) + ((seg & 1) << 9);
      dma16(src, dst);
    }
    __syncthreads();
#pragma unroll
    for (int c = 0; c < 4; c++) {
      const unsigned short* lphi = SB + c * 2048;
      const unsigned short* lg = SB + c * 2048 + 1024;
      bf16x8 pA0 = *(const bf16x8*)(lphi + (quad << 8) + row16 * 8);
      bf16x8 pA1 = *(const bf16x8*)(lphi + (quad << 8) + (row16 + 16) * 8);
      bf16x8 gA0 = *(const bf16x8*)(lg + (quad << 8) + row16 * 8);
      bf16x8 gA1 = *(const bf16x8*)(lg + (quad << 8) + (row16 + 16) * 8);
      const float* rp = rden + ((chunkb + ph * 4 + c) << 5) + (quad << 3);
      f32x4 r0 = *(const f32x4*)rp;
      f32x4 r1 = *(const f32x4*)(rp + 4);

      f32x4 f00 = __builtin_amdgcn_mfma_f32_16x16x32_bf16(pA0, tB0, zero, 0, 0, 0);
      f32x4 f10 = __builtin_amdgcn_mfma_f32_16x16x32_bf16(pA1, tB0, zero, 0, 0, 0);
      f32x4 f01 = __builtin_amdgcn_mfma_f32_16x16x32_bf16(pA0, tB1, zero, 0, 0, 0);
      f32x4 f11 = __builtin_amdgcn_mfma_f32_16x16x32_bf16(pA1, tB1, zero, 0, 0, 0);

      uint4 d0, d1;
      d0.x = pack_bf2(__builtin_amdgcn_exp2f(f00[0]) * r0[0],
                      __builtin_amdgcn_exp2f(f00[1]) * r0[1]);
      d0.y = pack_bf2(__builtin_amdgcn_exp2f(f00[2]) * r0[2],
                      __builtin_amdgcn_exp2f(f00[3]) * r0[3]);
      d0.z = pack_bf2(__builtin_amdgcn_exp2f(f10[0]) * r1[0],
                      __builtin_amdgcn_exp2f(f10[1]) * r1[1]);
      d0.w = pack_bf2(__builtin_amdgcn_exp2f(f10[2]) * r1[2],
                      __builtin_amdgcn_exp2f(f10[3]) * r1[3]);
      d1.x = pack_bf2(__builtin_amdgcn_exp2f(f01[0]) * r0[0],
                      __builtin_amdgcn_exp2f(f01[1]) * r0[1]);
      d1.y = pack_bf2(__builtin_amdgcn_exp2f(f01[2]) * r0[2],
                      __builtin_amdgcn_exp2f(f01[3]) * r0[3]);
      d1.z = pack_bf2(__builtin_amdgcn_exp2f(f11[0]) * r1[0],
                      __builtin_amdgcn_exp2f(f11[1]) * r1[1]);
      d1.w = pack_bf2(__builtin_amdgcn_exp2f(f11[2]) * r1[2],
                      __builtin_amdgcn_exp2f(f11[3]) * r1[3]);
      bf16x8 Pb0 = __builtin_bit_cast(bf16x8, d0);
      bf16x8 Pb1 = __builtin_bit_cast(bf16x8, d1);

      xa0 = __builtin_amdgcn_mfma_f32_16x16x32_bf16(gA0, Pb0, xa0, 0, 0, 0);
      xb0 = __builtin_amdgcn_mfma_f32_16x16x32_bf16(gA1, Pb0, xb0, 0, 0, 0);
      xa1 = __builtin_amdgcn_mfma_f32_16x16x32_bf16(gA0, Pb1, xa1, 0, 0, 0);
      xb1 = __builtin_amdgcn_mfma_f32_16x16x32_bf16(gA1, Pb1, xb1, 0, 0, 0);
    }
    __syncthreads();
  }

  // writeout: x1p[b*8+ms][i][n]; i = quad*4+r (+16 for xb*), n = nbase(+16)+row16
  size_t obase = ((size_t)(b * 8 + ms) * CI_) * N_;
#pragma unroll
  for (int r = 0; r < 4; r++) {
    size_t i0 = (size_t)(quad * 4 + r) * N_;
    size_t i1 = (size_t)(16 + quad * 4 + r) * N_;
    x1p[obase + i0 + nbase + row16] = f2bf_rne(xa0[r]);
    x1p[obase + i0 + nbase + 16 + row16] = f2bf_rne(xa1[r]);
    x1p[obase + i1 + nbase + row16] = f2bf_rne(xb0[r]);
    x1p[obase + i1 + nbase + 16 + row16] = f2bf_rne(xb1[r]);
  }
}

// ---------------------------------------------------------------------------
// K4: x1 = sum of 8 m-eighth partials (bf16); out = supp + ww.x1 + wb.
// Grid 512 = (b x 128 n-tiles of 32). 256 thr.
// ---------------------------------------------------------------------------
__global__ __launch_bounds__(256) void k4_out(
    const unsigned short* __restrict__ x1p, const float* __restrict__ supp,
    const float* __restrict__ ww, const float* __restrict__ wb,
    float* __restrict__ out)
{
  const int tid = threadIdx.x;
  const int b = blockIdx.x >> 7;
  const int n0 = (blockIdx.x & 127) << 5;

  __shared__ float x1L[CI_ * 33];
  __shared__ float wwL[C_ * 33];

  for (int e = tid; e < C_ * CI_; e += 256)
    wwL[(e >> 5) * 33 + (e & 31)] = ww[e];
  for (int e = tid; e < CI_ * 32; e += 256) {
    int i = e >> 5, nl = e & 31;
    size_t a = ((size_t)b * 8 * CI_ + i) * N_ + n0 + nl;
    float s = 0.f;
#pragma unroll
    for (int q = 0; q < 8; q++) s += bf2f(x1p[a + (size_t)q * CI_ * N_]);
    x1L[i * 33 + nl] = s;
  }
  __syncthreads();

  const int c = tid >> 2;
  const int nl0 = (tid & 3) << 3;
  float a[8];
  float bv = wb[c];
#pragma unroll
  for (int j = 0; j < 8; j++) a[j] = bv;
#pragma unroll 8
  for (int i = 0; i < CI_; i++) {
    float wv = wwL[c * 33 + i];
    const float* xr = &x1L[i * 33 + nl0];
#pragma unroll
    for (int j = 0; j < 8; j++) a[j] = fmaf(wv, xr[j], a[j]);
  }
  size_t ob = ((size_t)b * C_ + c) * N_ + n0 + nl0;
  float4 s0 = *(const float4*)(supp + ob);
  float4 s1 = *(const float4*)(supp + ob + 4);
  float4 o0, o1;
  o0.x = a[0] + s0.x; o0.y = a[1] + s0.y; o0.z = a[2] + s0.z; o0.w = a[3] + s0.w;
  o1.x = a[4] + s1.x; o1.y = a[5] + s1.y; o1.z = a[6] + s1.z; o1.w = a[7] + s1.w;
  *(float4*)(out + ob) = o0;
  *(float4*)(out + ob + 4) = o1;
}

extern "C" void kernel_launch(void* const* d_in, const int* in_sizes, int n_in,
                              void* d_out, int out_size, void* d_ws, size_t ws_size,
                              hipStream_t stream)
{
  const float* supp = (const float*)d_in[0];
  const float* ref  = (const float*)d_in[1];
  const float* tw   = (const float*)d_in[2];
  const float* tb   = (const float*)d_in[3];
  const float* pw   = (const float*)d_in[4];
  const float* pb   = (const float*)d_in[5];
  const float* gw   = (const float*)d_in[6];
  const float* gb   = (const float*)d_in[7];
  const float* ww   = (const float*)d_in[8];
  const float* wb   = (const float*)d_in[9];
  float* out = (float*)d_out;

  char* ws = (char*)d_ws;
  unsigned short* theta = (unsigned short*)ws;                   // 1 MB
  unsigned short* phi2  = (unsigned short*)(ws + (1u << 20));    // 1 MB (chunked)
  unsigned short* g2    = (unsigned short*)(ws + (2u << 20));    // 1 MB (chunked, sigma)
  float*          rden  = (float*)(ws + (3u << 20));             // 64 KB
  unsigned short* x1p   = (unsigned short*)(ws + (4u << 20));    // 8 MB (bf16)

  hipLaunchKernelGGL(k1_proj, dim3(768), dim3(256), 0, stream,
                     supp, ref, tw, tb, pw, pb, gw, gb, theta, phi2, g2);
  hipLaunchKernelGGL(k2_den, dim3(256), dim3(1024), 0, stream,
                     theta, phi2, rden);
  hipLaunchKernelGGL(k3_attn, dim3(1024), dim3(256), 0, stream,
                     theta, phi2, g2, rden, x1p);
  hipLaunchKernelGGL(k4_out, dim3(512), dim3(256), 0, stream,
                     x1p, supp, ww, wb, out);
}

// Round 8
// 117.311 us; speedup vs baseline: 1.0150x; 1.0150x over previous
//
#include <hip/hip_runtime.h>

#define C_ 64
#define CI_ 32
#define N_ 4096
#define LOG2E 1.4426950408889634f

typedef __attribute__((ext_vector_type(8))) short bf16x8;
typedef __attribute__((ext_vector_type(4))) float f32x4;

__device__ __forceinline__ unsigned short f2bf_rne(float f) {
  unsigned u = __builtin_bit_cast(unsigned, f);
  unsigned r = (u + 0x7FFFu + ((u >> 16) & 1u)) >> 16;
  return (unsigned short)r;
}
__device__ __forceinline__ unsigned pack_bf2(float lo, float hi) {
  unsigned a = (__builtin_bit_cast(unsigned, lo) + 0x8000u) >> 16;
  unsigned b = (__builtin_bit_cast(unsigned, hi) + 0x8000u) & 0xFFFF0000u;
  return a | b;
}
// async DMA global->LDS, 16B/lane; lds dst = wave-uniform base + lane*16
__device__ __forceinline__ void dma16(const void* gp, const void* lp) {
  __builtin_amdgcn_global_load_lds(
      (const __attribute__((address_space(1))) unsigned*)(unsigned long long)gp,
      (__attribute__((address_space(3))) unsigned*)(unsigned)(unsigned long long)lp,
      16, 0, 0);
}

// sigma (per 32-chunk): slot p=8q+j -> local idx 4q + (j&3) + 16*(j>>2).
// Chunked k-major layouts (2KB/chunk, DMA-contiguous, conflict-free ds_read):
//   phi2[b][ch][q][r=m_local][j]
//   g2  [b][ch][q][i][j]   value g[i][ch*32+sigma(8q+j)]
//   rden[b][ch][p] = 1/den[ch*32+sigma(p)]
//   ww2 [c][p]     = bf16( ww[c][sigma(p)] )   (for the MFMA epilogue)

// ---------------------------------------------------------------------------
// K1: projections. Grid 768 = (proj x b x 64 n-tiles of 64). 256 thr; wave =
// channel octet o, lane = one position. theta pre-scaled by log2(e).
// ---------------------------------------------------------------------------
__global__ __launch_bounds__(256) void k1_proj(
    const float* __restrict__ supp, const float* __restrict__ ref,
    const float* __restrict__ tw, const float* __restrict__ tb,
    const float* __restrict__ pw, const float* __restrict__ pb,
    const float* __restrict__ gw, const float* __restrict__ gb,
    unsigned short* __restrict__ theta, unsigned short* __restrict__ phi2,
    unsigned short* __restrict__ g2)
{
  const int proj = blockIdx.x >> 8;
  const int rr = blockIdx.x & 255;
  const int b = rr >> 6;
  const int n0 = (rr & 63) << 6;
  const int o = __builtin_amdgcn_readfirstlane(threadIdx.x >> 6);
  const int lane = threadIdx.x & 63;
  const int n = n0 + lane;

  __shared__ float gL[CI_][66];

  const float *W, *bias, *src;
  if (proj == 0)      { W = tw; bias = tb; src = supp; }
  else if (proj == 1) { W = pw; bias = pb; src = ref; }
  else                { W = gw; bias = gb; src = ref; }

  const float* x = src + (size_t)b * (C_ * N_) + n;
  const float* Wo = W + o * 8 * C_;
  float acc[8];
#pragma unroll
  for (int k = 0; k < 8; k++) acc[k] = bias[o * 8 + k];
#pragma unroll 8
  for (int c = 0; c < C_; c++) {
    float v = x[(size_t)c * N_];
#pragma unroll
    for (int k = 0; k < 8; k++) acc[k] = fmaf(Wo[k * C_ + c], v, acc[k]);
  }

  if (proj == 0) {
    unsigned pk[4];
#pragma unroll
    for (int k = 0; k < 4; k++)
      pk[k] = (unsigned)f2bf_rne(acc[2 * k] * LOG2E) |
              ((unsigned)f2bf_rne(acc[2 * k + 1] * LOG2E) << 16);
    *(uint4*)(theta + (((size_t)b * N_ + n) << 5) + o * 8) = *(uint4*)pk;
  } else if (proj == 1) {
    unsigned pk[4];
#pragma unroll
    for (int k = 0; k < 4; k++)
      pk[k] = (unsigned)f2bf_rne(acc[2 * k]) |
              ((unsigned)f2bf_rne(acc[2 * k + 1]) << 16);
    size_t off = (((size_t)b * 128 + (n >> 5)) << 10) + o * 256 + (n & 31) * 8;
    *(uint4*)(phi2 + off) = *(uint4*)pk;
  } else {
#pragma unroll
    for (int k = 0; k < 8; k++) gL[o * 8 + k][lane] = acc[k];
    __syncthreads();
    const int t = threadIdx.x;
    const int c = t >> 7;
    const int rr2 = t & 127;
    const int q = rr2 >> 5;
    const int i = rr2 & 31;
    const float* g0 = &gL[i][c * 32 + 4 * q];
    unsigned pk[4];
    pk[0] = pack_bf2(g0[0], g0[1]);
    pk[1] = pack_bf2(g0[2], g0[3]);
    pk[2] = pack_bf2(g0[16], g0[17]);
    pk[3] = pack_bf2(g0[18], g0[19]);
    size_t off = (((size_t)b * 128 + (n0 >> 5) + c) << 10) + rr2 * 8;
    *(uint4*)(g2 + off) = *(uint4*)pk;
  }
}

// ---------------------------------------------------------------------------
// K2: den[m] = sum_n exp2(f'); writes rden (sigma-ordered reciprocals).
// Block 0 also emits ww2 (sigma-permuted bf16 output weights).
// Grid 256 = (b x 64 m-tiles of 64). 16 waves = 256-n slices.
// ---------------------------------------------------------------------------
__global__ __launch_bounds__(1024) void k2_den(
    const unsigned short* __restrict__ theta, const unsigned short* __restrict__ phi2,
    const float* __restrict__ ww, float* __restrict__ rden,
    unsigned short* __restrict__ ww2)
{
  const int tid = threadIdx.x;
  const int wave = tid >> 6;
  const int lane = tid & 63;
  const int b = blockIdx.x >> 6;
  const int mbase = (blockIdx.x & 63) << 6;
  const int row16 = lane & 15;
  const int quad = lane >> 4;

  if (blockIdx.x == 0) {
    for (int e = tid; e < C_ * CI_; e += 1024) {
      int p = e & 31;
      int i = 4 * ((p >> 3) & 3) + (p & 3) + 16 * ((p >> 2) & 1);
      ww2[e] = f2bf_rne(ww[(e >> 5) * CI_ + i]);
    }
  }

  bf16x8 bf[4];
#pragma unroll
  for (int f = 0; f < 4; f++) {
    int ch = (mbase >> 5) + (f >> 1);
    int r = ((f & 1) << 4) + row16;
    bf[f] = *(const bf16x8*)(phi2 +
        (((size_t)b * 128 + ch) << 10) + (quad << 8) + r * 8);
  }

  const unsigned short* abase = theta +
      (((size_t)b * N_ + wave * 256 + row16) << 5) + (quad << 3);

  f32x4 zero = {0.f, 0.f, 0.f, 0.f};
  float dd[16];
#pragma unroll
  for (int k = 0; k < 16; k++) dd[k] = 0.f;

  bf16x8 a0 = *(const bf16x8*)abase;
  bf16x8 a1 = *(const bf16x8*)(abase + 512);
#pragma unroll 2
  for (int it = 0; it < 16; it++) {
    int itn = it + 2 <= 15 ? it + 2 : 15;
    bf16x8 an = *(const bf16x8*)(abase + ((size_t)itn << 9));
#pragma unroll
    for (int f = 0; f < 4; f++) {
      f32x4 ff = __builtin_amdgcn_mfma_f32_16x16x32_bf16(a0, bf[f], zero, 0, 0, 0);
#pragma unroll
      for (int r = 0; r < 4; r++) dd[f * 4 + r] += __builtin_amdgcn_exp2f(ff[r]);
    }
    a0 = a1; a1 = an;
  }

  __shared__ float denp[16][64];
#pragma unroll
  for (int f = 0; f < 4; f++) {
    float v = (dd[f * 4] + dd[f * 4 + 1]) + (dd[f * 4 + 2] + dd[f * 4 + 3]);
    v += __shfl_xor(v, 16);
    v += __shfl_xor(v, 32);
    if (lane < 16) denp[wave][f * 16 + lane] = v;
  }
  __syncthreads();

  if (tid < 64) {
    int p = tid;
    int q = (p >> 3) & 3, j = p & 7;
    int ml = (p & 32) + 4 * q + (j & 3) + ((j >> 2) << 4);
    float den = 0.f;
#pragma unroll
    for (int w = 0; w < 16; w++) den += denp[w][ml];
    rden[(((size_t)b * 128 + (mbase >> 5) + (p >> 5)) << 5) + (p & 31)] = 1.0f / den;
  }
}

// ---------------------------------------------------------------------------
// K3: full attention + output projection + residual, one block per
// (b, 64-n tile). Grid 256 x 1024 thr = 16 waves: wave = (ns 0..3: 16 n,
// q 0..3: m-quarter of 32 chunks). 32 phases: DMA next phase's 16KB
// (phi+g chunk per quarter) into the spare buffer, compute current, barrier.
// Epilogue: cross-quarter combine via LDS, then 4 MFMAs with A=ww2 project
// x1->out (+wb+supp). Zero scalar-LDS epilogue, no x1 round-trip.
// ---------------------------------------------------------------------------
__global__ __launch_bounds__(1024) void k3_attn(
    const unsigned short* __restrict__ theta, const unsigned short* __restrict__ phi2,
    const unsigned short* __restrict__ g2, const float* __restrict__ rden,
    const unsigned short* __restrict__ ww2, const float* __restrict__ wb,
    const float* __restrict__ supp, float* __restrict__ out)
{
  const int tid = threadIdx.x;
  const int w = tid >> 6;
  const int lane = tid & 63;
  const int b = blockIdx.x >> 6;
  const int n0 = (blockIdx.x & 63) << 6;
  const int ns = w & 3;
  const int q = w >> 2;
  const int row16 = lane & 15;
  const int quad = lane >> 4;

  __shared__ __align__(16) unsigned short SB[2][4][2048];  // 32 KB

  bf16x8 tB = *(const bf16x8*)(theta +
      (((size_t)b * N_ + n0 + ns * 16 + row16) << 5) + (quad << 3));

  const size_t chb = (size_t)b * 128;
  // stage assignment: wave w stages 1KB segment (q2 = w>>2, part = w&3)
  const int sq = w >> 2;
  const int sp = w & 3;

  f32x4 zero = {0.f, 0.f, 0.f, 0.f};
  f32x4 xa = zero, xb = zero;

  // prologue: stage phase 0 into buf 0
  {
    const unsigned short* src = (sp >= 2 ? g2 : phi2) +
        ((chb + sq * 32) << 10) + ((size_t)(sp & 1) << 9) + lane * 8;
    dma16(src, &SB[0][sq][(sp >= 2 ? 1024 : 0) + ((sp & 1) << 9)]);
  }
  __syncthreads();

  for (int ph = 0; ph < 32; ph++) {
    const int buf = ph & 1;
    if (ph + 1 < 32) {
      const unsigned short* src = (sp >= 2 ? g2 : phi2) +
          ((chb + sq * 32 + ph + 1) << 10) + ((size_t)(sp & 1) << 9) + lane * 8;
      dma16(src, &SB[buf ^ 1][sq][(sp >= 2 ? 1024 : 0) + ((sp & 1) << 9)]);
    }
    const unsigned short* base = &SB[buf][q][0];
    bf16x8 pA0 = *(const bf16x8*)(base + (quad << 8) + row16 * 8);
    bf16x8 pA1 = *(const bf16x8*)(base + (quad << 8) + (row16 + 16) * 8);
    bf16x8 gA0 = *(const bf16x8*)(base + 1024 + (quad << 8) + row16 * 8);
    bf16x8 gA1 = *(const bf16x8*)(base + 1024 + (quad << 8) + (row16 + 16) * 8);
    const float* rp = rden + ((chb + q * 32 + ph) << 5) + (quad << 3);
    f32x4 r0 = *(const f32x4*)rp;
    f32x4 r1 = *(const f32x4*)(rp + 4);

    f32x4 f0 = __builtin_amdgcn_mfma_f32_16x16x32_bf16(pA0, tB, zero, 0, 0, 0);
    f32x4 f1 = __builtin_amdgcn_mfma_f32_16x16x32_bf16(pA1, tB, zero, 0, 0, 0);

    uint4 d;
    d.x = pack_bf2(__builtin_amdgcn_exp2f(f0[0]) * r0[0],
                   __builtin_amdgcn_exp2f(f0[1]) * r0[1]);
    d.y = pack_bf2(__builtin_amdgcn_exp2f(f0[2]) * r0[2],
                   __builtin_amdgcn_exp2f(f0[3]) * r0[3]);
    d.z = pack_bf2(__builtin_amdgcn_exp2f(f1[0]) * r1[0],
                   __builtin_amdgcn_exp2f(f1[1]) * r1[1]);
    d.w = pack_bf2(__builtin_amdgcn_exp2f(f1[2]) * r1[2],
                   __builtin_amdgcn_exp2f(f1[3]) * r1[3]);
    bf16x8 Pb = __builtin_bit_cast(bf16x8, d);

    xa = __builtin_amdgcn_mfma_f32_16x16x32_bf16(gA0, Pb, xa, 0, 0, 0);
    xb = __builtin_amdgcn_mfma_f32_16x16x32_bf16(gA1, Pb, xb, 0, 0, 0);
    __syncthreads();
  }

  // cross-quarter combine: quarters 1..3 spill to LDS (aliases SB), q0 sums
  float* part = (float*)SB;
  if (q) {
    float* dst = part + ((((q - 1) * 4 + ns) * 64 + lane) << 3);
#pragma unroll
    for (int r = 0; r < 4; r++) { dst[r] = xa[r]; dst[4 + r] = xb[r]; }
  }
  __syncthreads();
  if (q == 0) {
#pragma unroll
    for (int e = 0; e < 3; e++) {
      const float* s = part + (((e * 4 + ns) * 64 + lane) << 3);
#pragma unroll
      for (int r = 0; r < 4; r++) { xa[r] += s[r]; xb[r] += s[4 + r]; }
    }
    uint4 d;
    d.x = pack_bf2(xa[0], xa[1]);
    d.y = pack_bf2(xa[2], xa[3]);
    d.z = pack_bf2(xb[0], xb[1]);
    d.w = pack_bf2(xb[2], xb[3]);
    bf16x8 Bx = __builtin_bit_cast(bf16x8, d);
    const int nloc = n0 + ns * 16 + row16;
#pragma unroll
    for (int ct = 0; ct < 4; ct++) {
      bf16x8 aw = *(const bf16x8*)(ww2 + (ct * 16 + row16) * CI_ + (quad << 3));
      f32x4 o = __builtin_amdgcn_mfma_f32_16x16x32_bf16(aw, Bx, zero, 0, 0, 0);
#pragma unroll
      for (int r = 0; r < 4; r++) {
        int c = ct * 16 + quad * 4 + r;
        size_t ob = ((size_t)b * C_ + c) * N_ + nloc;
        out[ob] = o[r] + wb[c] + supp[ob];
      }
    }
  }
}

extern "C" void kernel_launch(void* const* d_in, const int* in_sizes, int n_in,
                              void* d_out, int out_size, void* d_ws, size_t ws_size,
                              hipStream_t stream)
{
  const float* supp = (const float*)d_in[0];
  const float* ref  = (const float*)d_in[1];
  const float* tw   = (const float*)d_in[2];
  const float* tb   = (const float*)d_in[3];
  const float* pw   = (const float*)d_in[4];
  const float* pb   = (const float*)d_in[5];
  const float* gw   = (const float*)d_in[6];
  const float* gb   = (const float*)d_in[7];
  const float* ww   = (const float*)d_in[8];
  const float* wb   = (const float*)d_in[9];
  float* out = (float*)d_out;

  char* ws = (char*)d_ws;
  unsigned short* theta = (unsigned short*)ws;                       // 1 MB
  unsigned short* phi2  = (unsigned short*)(ws + (1u << 20));        // 1 MB
  unsigned short* g2    = (unsigned short*)(ws + (2u << 20));        // 1 MB
  float*          rden  = (float*)(ws + (3u << 20));                 // 64 KB
  unsigned short* ww2   = (unsigned short*)(ws + (3u << 20) + 65536);// 4 KB

  hipLaunchKernelGGL(k1_proj, dim3(768), dim3(256), 0, stream,
                     supp, ref, tw, tb, pw, pb, gw, gb, theta, phi2, g2);
  hipLaunchKernelGGL(k2_den, dim3(256), dim3(1024), 0, stream,
                     theta, phi2, ww, rden, ww2);
  hipLaunchKernelGGL(k3_attn, dim3(256), dim3(1024), 0, stream,
                     theta, phi2, g2, rden, ww2, wb, supp, out);
}

// Round 9
// 115.306 us; speedup vs baseline: 1.0327x; 1.0174x over previous
//
#include <hip/hip_runtime.h>

#define C_ 64
#define CI_ 32
#define N_ 4096
#define LOG2E 1.4426950408889634f

typedef __attribute__((ext_vector_type(8))) short bf16x8;
typedef __attribute__((ext_vector_type(4))) float f32x4;

__device__ __forceinline__ unsigned short f2bf_rne(float f) {
  unsigned u = __builtin_bit_cast(unsigned, f);
  unsigned r = (u + 0x7FFFu + ((u >> 16) & 1u)) >> 16;
  return (unsigned short)r;
}
__device__ __forceinline__ unsigned pack_bf2(float lo, float hi) {
  unsigned a = (__builtin_bit_cast(unsigned, lo) + 0x8000u) >> 16;
  unsigned b = (__builtin_bit_cast(unsigned, hi) + 0x8000u) & 0xFFFF0000u;
  return a | b;
}
// async DMA global->LDS, 16B/lane; lds dst = wave-uniform base (+lane*16 by HW)
__device__ __forceinline__ void dma16(const void* gp, const void* lp) {
  __builtin_amdgcn_global_load_lds(
      (const __attribute__((address_space(1))) unsigned*)(unsigned long long)gp,
      (__attribute__((address_space(3))) unsigned*)(unsigned)(unsigned long long)lp,
      16, 0, 0);
}

// sigma (per 32-chunk): slot p=8q+j -> local idx 4q + (j&3) + 16*(j>>2).
//   phi2[b][ch][q][r=m_local][j]           (2KB/chunk, DMA-contiguous)
//   g2  [b][ch][q][i][j]  = g[i][ch*32+sigma(8q+j)]
//   den [b][ch][p]        (fp32, atomically accumulated; K3 takes rcp)
//   ww2 [c][p]            = bf16( ww[c][sigma(p)] )

// ---------------------------------------------------------------------------
// K1: projections. Grid 768 = (proj x b x 64 n-tiles of 64). 256 thr; wave =
// channel octet o, lane = one position. theta pre-scaled by log2(e).
// ---------------------------------------------------------------------------
__global__ __launch_bounds__(256) void k1_proj(
    const float* __restrict__ supp, const float* __restrict__ ref,
    const float* __restrict__ tw, const float* __restrict__ tb,
    const float* __restrict__ pw, const float* __restrict__ pb,
    const float* __restrict__ gw, const float* __restrict__ gb,
    unsigned short* __restrict__ theta, unsigned short* __restrict__ phi2,
    unsigned short* __restrict__ g2)
{
  const int proj = blockIdx.x >> 8;
  const int rr = blockIdx.x & 255;
  const int b = rr >> 6;
  const int n0 = (rr & 63) << 6;
  const int o = __builtin_amdgcn_readfirstlane(threadIdx.x >> 6);
  const int lane = threadIdx.x & 63;
  const int n = n0 + lane;

  __shared__ float gL[CI_][66];

  const float *W, *bias, *src;
  if (proj == 0)      { W = tw; bias = tb; src = supp; }
  else if (proj == 1) { W = pw; bias = pb; src = ref; }
  else                { W = gw; bias = gb; src = ref; }

  const float* x = src + (size_t)b * (C_ * N_) + n;
  const float* Wo = W + o * 8 * C_;
  float acc[8];
#pragma unroll
  for (int k = 0; k < 8; k++) acc[k] = bias[o * 8 + k];
#pragma unroll 8
  for (int c = 0; c < C_; c++) {
    float v = x[(size_t)c * N_];
#pragma unroll
    for (int k = 0; k < 8; k++) acc[k] = fmaf(Wo[k * C_ + c], v, acc[k]);
  }

  if (proj == 0) {
    unsigned pk[4];
#pragma unroll
    for (int k = 0; k < 4; k++)
      pk[k] = (unsigned)f2bf_rne(acc[2 * k] * LOG2E) |
              ((unsigned)f2bf_rne(acc[2 * k + 1] * LOG2E) << 16);
    *(uint4*)(theta + (((size_t)b * N_ + n) << 5) + o * 8) = *(uint4*)pk;
  } else if (proj == 1) {
    unsigned pk[4];
#pragma unroll
    for (int k = 0; k < 4; k++)
      pk[k] = (unsigned)f2bf_rne(acc[2 * k]) |
              ((unsigned)f2bf_rne(acc[2 * k + 1]) << 16);
    size_t off = (((size_t)b * 128 + (n >> 5)) << 10) + o * 256 + (n & 31) * 8;
    *(uint4*)(phi2 + off) = *(uint4*)pk;
  } else {
#pragma unroll
    for (int k = 0; k < 8; k++) gL[o * 8 + k][lane] = acc[k];
    __syncthreads();
    const int t = threadIdx.x;
    const int c = t >> 7;
    const int rr2 = t & 127;
    const int q = rr2 >> 5;
    const int i = rr2 & 31;
    const float* g0 = &gL[i][c * 32 + 4 * q];
    unsigned pk[4];
    pk[0] = pack_bf2(g0[0], g0[1]);
    pk[1] = pack_bf2(g0[2], g0[3]);
    pk[2] = pack_bf2(g0[16], g0[17]);
    pk[3] = pack_bf2(g0[18], g0[19]);
    size_t off = (((size_t)b * 128 + (n0 >> 5) + c) << 10) + rr2 * 8;
    *(uint4*)(g2 + off) = *(uint4*)pk;
  }
}

// ---------------------------------------------------------------------------
// K2: den[m] += sum over this block's n-quarter of exp2(f'). m97 pattern:
// grid 1024 = (b x 4 n-quarters x 64 m-tiles); 256 thr = 4 waves; wave =
// 16-m slice, persistent phi B-frag; theta DMA double-buffered (4KB/phase,
// 64 n-rows, shared by all waves), 16 phases. Partials -> global atomicAdd.
// Block 0 also emits ww2.
// ---------------------------------------------------------------------------
__global__ __launch_bounds__(256) void k2_den(
    const unsigned short* __restrict__ theta, const unsigned short* __restrict__ phi2,
    const float* __restrict__ ww, float* __restrict__ den,
    unsigned short* __restrict__ ww2)
{
  const int mt = blockIdx.x & 63;
  const int nq = (blockIdx.x >> 6) & 3;
  const int b = blockIdx.x >> 8;
  const int tid = threadIdx.x;
  const int w = tid >> 6;
  const int lane = tid & 63;
  const int row16 = lane & 15;
  const int quad = lane >> 4;

  if (blockIdx.x == 0) {
    for (int e = tid; e < C_ * CI_; e += 256) {
      int p = e & 31;
      int i = 4 * ((p >> 3) & 3) + (p & 3) + 16 * ((p >> 2) & 1);
      ww2[e] = f2bf_rne(ww[(e >> 5) * CI_ + i]);
    }
  }

  __shared__ __align__(16) unsigned short TH[2][2048];   // 2 x 4KB

  // persistent B-frag: wave's m-16 = mt*64 + w*16 + row16
  bf16x8 bf = *(const bf16x8*)(phi2 +
      (((size_t)b * 128 + mt * 2 + (w >> 1)) << 10) + (quad << 8) +
      ((w & 1) * 16 + row16) * 8);

  const unsigned short* thbase = theta + (((size_t)b * N_ + nq * 1024) << 5);

  // prologue: stage phase 0 (wave w -> its 1KB segment)
  dma16(thbase + w * 512 + lane * 8, &TH[0][w * 512]);
  __syncthreads();

  f32x4 zero = {0.f, 0.f, 0.f, 0.f};
  float ds4[4] = {0.f, 0.f, 0.f, 0.f};

  for (int ph = 0; ph < 16; ph++) {
    const int buf = ph & 1;
    if (ph + 1 < 16)
      dma16(thbase + (ph + 1) * 2048 + w * 512 + lane * 8, &TH[buf ^ 1][w * 512]);
#pragma unroll
    for (int s = 0; s < 4; s++) {
      bf16x8 af = *(const bf16x8*)(&TH[buf][s * 512 + row16 * 32 + quad * 8]);
      f32x4 ff = __builtin_amdgcn_mfma_f32_16x16x32_bf16(af, bf, zero, 0, 0, 0);
#pragma unroll
      for (int r = 0; r < 4; r++) ds4[r] += __builtin_amdgcn_exp2f(ff[r]);
    }
    __syncthreads();
  }

  float v = (ds4[0] + ds4[1]) + (ds4[2] + ds4[3]);
  v += __shfl_xor(v, 16);
  v += __shfl_xor(v, 32);
  if (lane < 16) {
    int ml64 = w * 16 + lane;
    int ch = mt * 2 + (ml64 >> 5);
    int local = ml64 & 31;
    int q = (local & 15) >> 2;
    int j = (local & 3) | (((local >> 4) & 1) << 2);
    atomicAdd(&den[(((size_t)b * 128 + ch) << 5) + 8 * q + j], v);
  }
}

// ---------------------------------------------------------------------------
// K3: full attention + output projection + residual. Grid 256 = (b x 64-n
// tile) x 1024 thr = 16 waves (ns x m-quarter q). rden built once per block
// into LDS (v_rcp). 16 phases x 2 chunks: DMA next phase's 32KB into spare
// buffer, compute current, barrier. MFMA epilogue with A=ww2.
// LDS 80KB -> 2 blocks/CU.
// ---------------------------------------------------------------------------
__global__ __launch_bounds__(1024) void k3_attn(
    const unsigned short* __restrict__ theta, const unsigned short* __restrict__ phi2,
    const unsigned short* __restrict__ g2, const float* __restrict__ den,
    const unsigned short* __restrict__ ww2, const float* __restrict__ wb,
    const float* __restrict__ supp, float* __restrict__ out)
{
  const int tid = threadIdx.x;
  const int w = tid >> 6;
  const int lane = tid & 63;
  const int b = blockIdx.x >> 6;
  const int n0 = (blockIdx.x & 63) << 6;
  const int ns = w & 3;
  const int q = w >> 2;
  const int row16 = lane & 15;
  const int quad = lane >> 4;

  __shared__ __align__(16) unsigned short SB[2][4][4096];  // 64 KB
  __shared__ float rdenL[4096];                            // 16 KB

  for (int e = tid; e < 4096; e += 1024)
    rdenL[e] = __builtin_amdgcn_rcpf(den[((size_t)b << 12) + e]);

  bf16x8 tB = *(const bf16x8*)(theta +
      (((size_t)b * N_ + n0 + ns * 16 + row16) << 5) + (quad << 3));

  const size_t chb = (size_t)b * 128;
  // DMA assignment: idx = w*2+s in 0..31: q2=idx>>3, cc=(idx>>2)&1, part=idx&3
  const int sq = w >> 2;        // reuse q for staging quarter too (w*2+s>>3 == w>>2)

  f32x4 zero = {0.f, 0.f, 0.f, 0.f};
  f32x4 xa = zero, xb = zero;

  // prologue: stage phase 0 into buf 0
#pragma unroll
  for (int s = 0; s < 2; s++) {
    int idx = w * 2 + s;
    int cc = (idx >> 2) & 1;
    int part = idx & 3;                  // 0:phi-lo 1:phi-hi 2:g-lo 3:g-hi
    const unsigned short* src = (part >= 2 ? g2 : phi2) +
        ((chb + sq * 32 + cc) << 10) + ((size_t)(part & 1) << 9) + lane * 8;
    dma16(src, &SB[0][sq][cc * 2048 + (part >= 2 ? 1024 : 0) + ((part & 1) << 9)]);
  }
  __syncthreads();

  for (int ph = 0; ph < 16; ph++) {
    const int buf = ph & 1;
    if (ph + 1 < 16) {
#pragma unroll
      for (int s = 0; s < 2; s++) {
        int idx = w * 2 + s;
        int cc = (idx >> 2) & 1;
        int part = idx & 3;
        const unsigned short* src = (part >= 2 ? g2 : phi2) +
            ((chb + sq * 32 + (ph + 1) * 2 + cc) << 10) + ((size_t)(part & 1) << 9) + lane * 8;
        dma16(src, &SB[buf ^ 1][sq][cc * 2048 + (part >= 2 ? 1024 : 0) + ((part & 1) << 9)]);
      }
    }
#pragma unroll
    for (int cc = 0; cc < 2; cc++) {
      const unsigned short* base = &SB[buf][q][cc * 2048];
      bf16x8 pA0 = *(const bf16x8*)(base + (quad << 8) + row16 * 8);
      bf16x8 pA1 = *(const bf16x8*)(base + (quad << 8) + (row16 + 16) * 8);
      bf16x8 gA0 = *(const bf16x8*)(base + 1024 + (quad << 8) + row16 * 8);
      bf16x8 gA1 = *(const bf16x8*)(base + 1024 + (quad << 8) + (row16 + 16) * 8);
      const float* rp = &rdenL[((q * 32 + ph * 2 + cc) << 5) + (quad << 3)];
      f32x4 r0 = *(const f32x4*)rp;
      f32x4 r1 = *(const f32x4*)(rp + 4);

      f32x4 f0 = __builtin_amdgcn_mfma_f32_16x16x32_bf16(pA0, tB, zero, 0, 0, 0);
      f32x4 f1 = __builtin_amdgcn_mfma_f32_16x16x32_bf16(pA1, tB, zero, 0, 0, 0);

      uint4 d;
      d.x = pack_bf2(__builtin_amdgcn_exp2f(f0[0]) * r0[0],
                     __builtin_amdgcn_exp2f(f0[1]) * r0[1]);
      d.y = pack_bf2(__builtin_amdgcn_exp2f(f0[2]) * r0[2],
                     __builtin_amdgcn_exp2f(f0[3]) * r0[3]);
      d.z = pack_bf2(__builtin_amdgcn_exp2f(f1[0]) * r1[0],
                     __builtin_amdgcn_exp2f(f1[1]) * r1[1]);
      d.w = pack_bf2(__builtin_amdgcn_exp2f(f1[2]) * r1[2],
                     __builtin_amdgcn_exp2f(f1[3]) * r1[3]);
      bf16x8 Pb = __builtin_bit_cast(bf16x8, d);

      xa = __builtin_amdgcn_mfma_f32_16x16x32_bf16(gA0, Pb, xa, 0, 0, 0);
      xb = __builtin_amdgcn_mfma_f32_16x16x32_bf16(gA1, Pb, xb, 0, 0, 0);
    }
    __syncthreads();
  }

  // cross-quarter combine: quarters 1..3 spill to LDS (aliases SB), q0 sums
  float* part = (float*)SB;
  if (q) {
    float* dst = part + ((((q - 1) * 4 + ns) * 64 + lane) << 3);
#pragma unroll
    for (int r = 0; r < 4; r++) { dst[r] = xa[r]; dst[4 + r] = xb[r]; }
  }
  __syncthreads();
  if (q == 0) {
#pragma unroll
    for (int e = 0; e < 3; e++) {
      const float* s = part + (((e * 4 + ns) * 64 + lane) << 3);
#pragma unroll
      for (int r = 0; r < 4; r++) { xa[r] += s[r]; xb[r] += s[4 + r]; }
    }
    uint4 d;
    d.x = pack_bf2(xa[0], xa[1]);
    d.y = pack_bf2(xa[2], xa[3]);
    d.z = pack_bf2(xb[0], xb[1]);
    d.w = pack_bf2(xb[2], xb[3]);
    bf16x8 Bx = __builtin_bit_cast(bf16x8, d);
    const int nloc = n0 + ns * 16 + row16;
#pragma unroll
    for (int ct = 0; ct < 4; ct++) {
      bf16x8 aw = *(const bf16x8*)(ww2 + (ct * 16 + row16) * CI_ + (quad << 3));
      f32x4 o = __builtin_amdgcn_mfma_f32_16x16x32_bf16(aw, Bx, zero, 0, 0, 0);
#pragma unroll
      for (int r = 0; r < 4; r++) {
        int c = ct * 16 + quad * 4 + r;
        size_t ob = ((size_t)b * C_ + c) * N_ + nloc;
        out[ob] = o[r] + wb[c] + supp[ob];
      }
    }
  }
}

extern "C" void kernel_launch(void* const* d_in, const int* in_sizes, int n_in,
                              void* d_out, int out_size, void* d_ws, size_t ws_size,
                              hipStream_t stream)
{
  const float* supp = (const float*)d_in[0];
  const float* ref  = (const float*)d_in[1];
  const float* tw   = (const float*)d_in[2];
  const float* tb   = (const float*)d_in[3];
  const float* pw   = (const float*)d_in[4];
  const float* pb   = (const float*)d_in[5];
  const float* gw   = (const float*)d_in[6];
  const float* gb   = (const float*)d_in[7];
  const float* ww   = (const float*)d_in[8];
  const float* wb   = (const float*)d_in[9];
  float* out = (float*)d_out;

  char* ws = (char*)d_ws;
  unsigned short* theta = (unsigned short*)ws;                       // 1 MB
  unsigned short* phi2  = (unsigned short*)(ws + (1u << 20));        // 1 MB
  unsigned short* g2    = (unsigned short*)(ws + (2u << 20));        // 1 MB
  float*          den   = (float*)(ws + (3u << 20));                 // 64 KB
  unsigned short* ww2   = (unsigned short*)(ws + (3u << 20) + 65536);// 4 KB

  hipMemsetAsync(den, 0, 4 * 128 * 32 * sizeof(float), stream);
  hipLaunchKernelGGL(k1_proj, dim3(768), dim3(256), 0, stream,
                     supp, ref, tw, tb, pw, pb, gw, gb, theta, phi2, g2);
  hipLaunchKernelGGL(k2_den, dim3(1024), dim3(256), 0, stream,
                     theta, phi2, ww, den, ww2);
  hipLaunchKernelGGL(k3_attn, dim3(256), dim3(1024), 0, stream,
                     theta, phi2, g2, den, ww2, wb, supp, out);
}